// Round 5
// baseline (407.846 us; speedup 1.0000x reference)
//
#include <hip/hip_runtime.h>

typedef float  floatx4  __attribute__((ext_vector_type(4)));
typedef short  bf16x8   __attribute__((ext_vector_type(8)));
typedef float  facc4    __attribute__((ext_vector_type(4)));

__device__ __forceinline__ unsigned short f2bf(float f) {
  unsigned u = __builtin_bit_cast(unsigned, f);
  u = u + 0x7fffu + ((u >> 16) & 1u);   // round-to-nearest-even
  return (unsigned short)(u >> 16);
}

// ---------------- K1: chunk partial products (unchanged) ----------------
template <int I0, int I1>
__device__ void gen_chunk(const float* __restrict__ ang, float* __restrict__ out,
                          float* lcs, int tid) {
  constexpr int P0 = I0 * 127 - I0 * (I0 - 1) / 2;
  constexpr int P1 = I1 * 127 - I1 * (I1 - 1) / 2;
  constexpr int NROT = P1 - P0;
  for (int idx = tid; idx < NROT; idx += 256) {
    float s, c;
    sincosf(ang[P0 + idx], &s, &c);
    lcs[2 * idx] = c;
    lcs[2 * idx + 1] = s;
  }
  __syncthreads();
  if (tid >= 128) return;
  float w[128];
#pragma unroll
  for (int k = 0; k < 128; ++k) w[k] = (k == tid) ? 1.0f : 0.0f;
#pragma unroll
  for (int i = I0; i < I1; ++i) {
    float wi = w[i];
#pragma unroll
    for (int j = i + 1; j < 128; ++j) {
      const int p = (i * 127 - (i * (i - 1)) / 2 + (j - i - 1)) - P0;
      const float2 cs2 = *(const float2*)(&lcs[2 * p]);
      const float c = cs2.x, s = cs2.y;
      const float wj = w[j];
      w[j] = fmaf(wj, c, -(wi * s));
      wi   = fmaf(wj, s, wi * c);
    }
    w[i] = wi;
  }
  floatx4* o = (floatx4*)(out + (size_t)tid * 128);
#pragma unroll
  for (int k = 0; k < 32; ++k) {
    floatx4 v;
    v[0] = w[4 * k]; v[1] = w[4 * k + 1]; v[2] = w[4 * k + 2]; v[3] = w[4 * k + 3];
    o[k] = v;
  }
}

__global__ __launch_bounds__(256) void k_wgen(const float* __restrict__ ang,
                                              float* __restrict__ out) {
  __shared__ float lcs[2144];
  const int tid = threadIdx.x;
  switch (blockIdx.x) {
    case 0:  gen_chunk<0,   8>(ang, out + 0 * 16384, lcs, tid); break;
    case 1:  gen_chunk<8,  17>(ang, out + 1 * 16384, lcs, tid); break;
    case 2:  gen_chunk<17, 27>(ang, out + 2 * 16384, lcs, tid); break;
    case 3:  gen_chunk<27, 37>(ang, out + 3 * 16384, lcs, tid); break;
    case 4:  gen_chunk<37, 49>(ang, out + 4 * 16384, lcs, tid); break;
    case 5:  gen_chunk<49, 64>(ang, out + 5 * 16384, lcs, tid); break;
    case 6:  gen_chunk<64, 82>(ang, out + 6 * 16384, lcs, tid); break;
    default: gen_chunk<82, 127>(ang, out + 7 * 16384, lcs, tid); break;
  }
}

// ---------------- K2: combine W = C0*...*C7 -> Wt bf16 [n][136] (unchanged) --------
__global__ __launch_bounds__(128) void k_combine(const float* __restrict__ chunks,
                                                 unsigned short* __restrict__ wt) {
  __shared__ float sv[128];
  const int r = blockIdx.x;
  const int t = threadIdx.x;
  float v = chunks[r * 128 + t];
  for (int m = 1; m < 8; ++m) {
    __syncthreads();
    sv[t] = v;
    __syncthreads();
    const float* Cm = chunks + m * 16384 + t;
    float a0 = 0.f, a1 = 0.f, a2 = 0.f, a3 = 0.f;
#pragma unroll
    for (int k = 0; k < 128; k += 4) {
      a0 = fmaf(sv[k],     Cm[(k)     * 128], a0);
      a1 = fmaf(sv[k + 1], Cm[(k + 1) * 128], a1);
      a2 = fmaf(sv[k + 2], Cm[(k + 2) * 128], a2);
      a3 = fmaf(sv[k + 3], Cm[(k + 3) * 128], a3);
    }
    v = (a0 + a1) + (a2 + a3);
  }
  wt[t * 136 + r] = f2bf(v);
}

// ---------------- K3: y = x @ W + bias ----------------
// Round-5 experiment: 32 waves/CU at the PROVEN traffic geometry.
//   grid 1024 x 512 threads (8 waves/block), 256 rows/block -> 4 blocks/CU x 8
//   waves = 32 waves/CU.  Round-0 structure: W in LDS (34.8 KB shared by 8
//   waves), wave-INDEPENDENT main loop (zero barriers after W staging), each
//   wave owns 32 rows = 2 groups of 16.  Loads/stores are 64 B per row per
//   instruction -- proven sector-efficient in r0/r2 (WRITE == y, FETCH == x/2).
__global__ __launch_bounds__(512, 8) void k_gemm(const float* __restrict__ x,
                                                 const unsigned short* __restrict__ wt,
                                                 const float* __restrict__ bias,
                                                 float* __restrict__ y) {
  __shared__ unsigned short sW[128 * 136];  // 34816 B
  __shared__ float sB[128];
  const int tid = threadIdx.x;
  {
    const floatx4* src = (const floatx4*)wt;
    floatx4* dst = (floatx4*)sW;
#pragma unroll
    for (int i2 = 0; i2 < 5; ++i2) {
      int idx = tid + i2 * 512;
      if (idx < 2176) dst[idx] = src[idx];
    }
    if (tid < 128) sB[tid] = bias[tid];
  }
  __syncthreads();

  const int wv = tid >> 6, lane = tid & 63;
  const int m16 = lane & 15, h = lane >> 4;

  // wave wv owns rows [bid*256 + wv*32, +32), processed as 2 groups of 16
  const size_t row0 = (size_t)blockIdx.x * 256 + wv * 32 + m16;
  const float* xr0 = x + row0 * 128;
  float* yr0 = y + row0 * 128;

  floatx4 a[8];
#pragma unroll
  for (int c = 0; c < 4; ++c) {  // prologue: group-0 loads
    a[2 * c]     = *(const floatx4*)(xr0 + c * 32 + h * 8);
    a[2 * c + 1] = *(const floatx4*)(xr0 + c * 32 + h * 8 + 4);
  }

#pragma unroll
  for (int g = 0; g < 2; ++g) {
    // convert current group's x to bf16 (frees a[] for the next prefetch)
    bf16x8 af[4];
#pragma unroll
    for (int c = 0; c < 4; ++c) {
#pragma unroll
      for (int q = 0; q < 8; ++q) {
        const float f = (q < 4) ? a[2 * c][q] : a[2 * c + 1][q - 4];
        af[c][q] = (short)f2bf(f);
      }
    }
    // prefetch group-1's x
    if (g == 0) {
      const float* xr = xr0 + 16 * 128;
#pragma unroll
      for (int c = 0; c < 4; ++c) {
        a[2 * c]     = *(const floatx4*)(xr + c * 32 + h * 8);
        a[2 * c + 1] = *(const floatx4*)(xr + c * 32 + h * 8 + 4);
      }
    }
    // acc init = bias (C operand): reg r holds feature t*16 + h*4 + r
    facc4 acc[8];
#pragma unroll
    for (int t = 0; t < 8; ++t) acc[t] = *(const facc4*)(sB + t * 16 + h * 4);
#pragma unroll
    for (int c = 0; c < 4; ++c) {
#pragma unroll
      for (int t = 0; t < 8; ++t) {
        // A[m=lane&15][k=h*8+j] = Wt[t*16+m16][c*32+h*8+j]
        const bf16x8 bw = *(const bf16x8*)(&sW[(t * 16 + m16) * 136 + c * 32 + h * 8]);
        acc[t] = __builtin_amdgcn_mfma_f32_16x16x32_bf16(bw, af[c], acc[t], 0, 0, 0);
      }
    }
    float* yr = yr0 + (size_t)g * 16 * 128;
#pragma unroll
    for (int t = 0; t < 8; ++t) {
      *(floatx4*)(yr + t * 16 + h * 4) = acc[t];  // 16B x 4 lanes = 64 B per row
    }
  }
}

extern "C" void kernel_launch(void* const* d_in, const int* in_sizes, int n_in,
                              void* d_out, int out_size, void* d_ws, size_t ws_size,
                              hipStream_t stream) {
  const float* x    = (const float*)d_in[0];
  const float* ang  = (const float*)d_in[1];
  const float* bias = (const float*)d_in[2];
  float* y = (float*)d_out;

  char* ws = (char*)d_ws;
  float* chunks      = (float*)ws;                      // 8 * 64 KiB = 524288 B
  unsigned short* wt = (unsigned short*)(ws + 524288);  // 34816 B

  k_wgen   <<<8,    256, 0, stream>>>(ang, chunks);
  k_combine<<<128,  128, 0, stream>>>(chunks, wt);
  k_gemm   <<<1024, 512, 0, stream>>>(x, wt, bias, y);
}

// Round 6
// 343.492 us; speedup vs baseline: 1.1874x; 1.1874x over previous
//
#include <hip/hip_runtime.h>

typedef float  floatx4  __attribute__((ext_vector_type(4)));
typedef short  bf16x8   __attribute__((ext_vector_type(8)));
typedef float  facc4    __attribute__((ext_vector_type(4)));
typedef unsigned short ushortx4 __attribute__((ext_vector_type(4)));

__device__ __forceinline__ unsigned short f2bf(float f) {
  unsigned u = __builtin_bit_cast(unsigned, f);
  u = u + 0x7fffu + ((u >> 16) & 1u);   // round-to-nearest-even
  return (unsigned short)(u >> 16);
}

// ---------------- K1: chunk partial products (unchanged) ----------------
template <int I0, int I1>
__device__ void gen_chunk(const float* __restrict__ ang, float* __restrict__ out,
                          float* lcs, int tid) {
  constexpr int P0 = I0 * 127 - I0 * (I0 - 1) / 2;
  constexpr int P1 = I1 * 127 - I1 * (I1 - 1) / 2;
  constexpr int NROT = P1 - P0;
  for (int idx = tid; idx < NROT; idx += 256) {
    float s, c;
    sincosf(ang[P0 + idx], &s, &c);
    lcs[2 * idx] = c;
    lcs[2 * idx + 1] = s;
  }
  __syncthreads();
  if (tid >= 128) return;
  float w[128];
#pragma unroll
  for (int k = 0; k < 128; ++k) w[k] = (k == tid) ? 1.0f : 0.0f;
#pragma unroll
  for (int i = I0; i < I1; ++i) {
    float wi = w[i];
#pragma unroll
    for (int j = i + 1; j < 128; ++j) {
      const int p = (i * 127 - (i * (i - 1)) / 2 + (j - i - 1)) - P0;
      const float2 cs2 = *(const float2*)(&lcs[2 * p]);
      const float c = cs2.x, s = cs2.y;
      const float wj = w[j];
      w[j] = fmaf(wj, c, -(wi * s));
      wi   = fmaf(wj, s, wi * c);
    }
    w[i] = wi;
  }
  floatx4* o = (floatx4*)(out + (size_t)tid * 128);
#pragma unroll
  for (int k = 0; k < 32; ++k) {
    floatx4 v;
    v[0] = w[4 * k]; v[1] = w[4 * k + 1]; v[2] = w[4 * k + 2]; v[3] = w[4 * k + 3];
    o[k] = v;
  }
}

__global__ __launch_bounds__(256) void k_wgen(const float* __restrict__ ang,
                                              float* __restrict__ out) {
  __shared__ float lcs[2144];
  const int tid = threadIdx.x;
  switch (blockIdx.x) {
    case 0:  gen_chunk<0,   8>(ang, out + 0 * 16384, lcs, tid); break;
    case 1:  gen_chunk<8,  17>(ang, out + 1 * 16384, lcs, tid); break;
    case 2:  gen_chunk<17, 27>(ang, out + 2 * 16384, lcs, tid); break;
    case 3:  gen_chunk<27, 37>(ang, out + 3 * 16384, lcs, tid); break;
    case 4:  gen_chunk<37, 49>(ang, out + 4 * 16384, lcs, tid); break;
    case 5:  gen_chunk<49, 64>(ang, out + 5 * 16384, lcs, tid); break;
    case 6:  gen_chunk<64, 82>(ang, out + 6 * 16384, lcs, tid); break;
    default: gen_chunk<82, 127>(ang, out + 7 * 16384, lcs, tid); break;
  }
}

// ---------------- K2: combine W = C0*...*C7 -> Wt bf16 [n][136] (unchanged) --------
__global__ __launch_bounds__(128) void k_combine(const float* __restrict__ chunks,
                                                 unsigned short* __restrict__ wt) {
  __shared__ float sv[128];
  const int r = blockIdx.x;
  const int t = threadIdx.x;
  float v = chunks[r * 128 + t];
  for (int m = 1; m < 8; ++m) {
    __syncthreads();
    sv[t] = v;
    __syncthreads();
    const float* Cm = chunks + m * 16384 + t;
    float a0 = 0.f, a1 = 0.f, a2 = 0.f, a3 = 0.f;
#pragma unroll
    for (int k = 0; k < 128; k += 4) {
      a0 = fmaf(sv[k],     Cm[(k)     * 128], a0);
      a1 = fmaf(sv[k + 1], Cm[(k + 1) * 128], a1);
      a2 = fmaf(sv[k + 2], Cm[(k + 2) * 128], a2);
      a3 = fmaf(sv[k + 3], Cm[(k + 3) * 128], a3);
    }
    v = (a0 + a1) + (a2 + a3);
  }
  wt[t * 136 + r] = f2bf(v);
}

// ---------------- K3: y = x @ W + bias ----------------
// Round-6: keep 32 waves/CU (grid 2048, lb(256,8) -- proven 3.5 TB/s), but fix
// the write-amplification: at 32 waves/CU, y-rows assembled from chunks of
// DIFFERENT instructions/waves get evicted as partial lines (RMW: extra WRITE
// ~= extra FETCH ~= 100 MB in r3/r4; 3.7x WRITE in r5).  Fix = block-level LDS
// transpose: all 4 waves deposit acc into a shared 16x128 fp32 sY tile, then
// 256 threads store 4-KB fully-contiguous spans (8 complete rows/instruction).
__global__ __launch_bounds__(256, 8) void k_gemm(const float* __restrict__ x,
                                                 const unsigned short* __restrict__ wt,
                                                 const float* __restrict__ bias,
                                                 float* __restrict__ y) {
  __shared__ unsigned short sX[2][2048];  // 2 x (16 rows x 128 cols) bf16, swizzled
  __shared__ float sY[16 * 128];          // block-level y transpose tile (8 KiB)

  const int tid = threadIdx.x;
  const int wv = tid >> 6, lane = tid & 63;
  const int m16 = lane & 15, h = lane >> 4;

  // --- W fragments (A operand) + bias fragments in registers, loaded once ---
  bf16x8 bw[2][4];
#pragma unroll
  for (int t = 0; t < 2; ++t)
#pragma unroll
    for (int c = 0; c < 4; ++c)
      bw[t][c] = *(const bf16x8*)(wt + (size_t)(wv * 32 + t * 16 + m16) * 136
                                     + c * 32 + h * 8);
  facc4 bfr[2];
#pragma unroll
  for (int t = 0; t < 2; ++t)
    bfr[t] = *(const facc4*)(bias + wv * 32 + t * 16 + h * 4);

  const float* xb = x + (size_t)blockIdx.x * 128 * 128;
  float*       yb = y + (size_t)blockIdx.x * 128 * 128;

  // staging geometry: thread stages 8 floats -> 8 bf16 (two b64 writes)
  const int r0 = tid >> 5;              // 0..7 (first half-tile row)
  const int c0 = (tid & 31) * 4;        // float col of both quads
  const unsigned sw0  = (unsigned)((r0 & 7) << 4);
  const unsigned stb0 = (unsigned)(r0 * 256 + ((c0 * 2) ^ sw0));
  const unsigned stb1 = stb0 + 2048;    // row r0+8: (r0+8)&7 == r0&7

  // sY geometry: write (row=m16, features wv*32+{0,16}+h*4), XOR-swizzled
  const unsigned syw  = (unsigned)(m16 * 512 + (((wv * 32 + h * 4) * 4) ^ ((m16 & 7) << 4)));
  const unsigned syw1 = (unsigned)(m16 * 512 + (((wv * 32 + 16 + h * 4) * 4) ^ ((m16 & 7) << 4)));

  // prologue: load tiles 0 (A) and 1 (B); stage tile 0
  floatx4 pA0 = *(const floatx4*)(xb + tid * 4);
  floatx4 pA1 = *(const floatx4*)(xb + 1024 + tid * 4);
  floatx4 pB0 = *(const floatx4*)(xb + 2048 + tid * 4);
  floatx4 pB1 = *(const floatx4*)(xb + 3072 + tid * 4);
  {
    ushortx4 q0, q1;
#pragma unroll
    for (int q = 0; q < 4; ++q) { q0[q] = f2bf(pA0[q]); q1[q] = f2bf(pA1[q]); }
    *(ushortx4*)((char*)&sX[0][0] + stb0) = q0;
    *(ushortx4*)((char*)&sX[0][0] + stb1) = q1;
  }
  __syncthreads();

#pragma unroll
  for (int it = 0; it < 8; ++it) {
    const int cur = it & 1;
    // B fragments: lane (m16,h) reads row m16, bf16 cols [c*32+h*8, +8)
    bf16x8 af[4];
#pragma unroll
    for (int c = 0; c < 4; ++c)
      af[c] = *(const bf16x8*)((const char*)&sX[cur][0] +
               (unsigned)(m16 * 256 + ((c * 64 + h * 16) ^ ((m16 & 7) << 4))));

    // issue tile it+2 loads (into the register set freed by last stage)
    if (it + 2 < 8) {
      const float* s2 = xb + (size_t)(it + 2) * 2048;
      if (cur == 0) {
        pA0 = *(const floatx4*)(s2 + tid * 4);
        pA1 = *(const floatx4*)(s2 + 1024 + tid * 4);
      } else {
        pB0 = *(const floatx4*)(s2 + tid * 4);
        pB1 = *(const floatx4*)(s2 + 1024 + tid * 4);
      }
    }
    // stage tile it+1 into sX[cur^1] (convert fp32 -> bf16 once, swizzled write)
    if (it + 1 < 8) {
      ushortx4 q0, q1;
      if (cur == 0) {
#pragma unroll
        for (int q = 0; q < 4; ++q) { q0[q] = f2bf(pB0[q]); q1[q] = f2bf(pB1[q]); }
      } else {
#pragma unroll
        for (int q = 0; q < 4; ++q) { q0[q] = f2bf(pA0[q]); q1[q] = f2bf(pA1[q]); }
      }
      *(ushortx4*)((char*)&sX[cur ^ 1][0] + stb0) = q0;
      *(ushortx4*)((char*)&sX[cur ^ 1][0] + stb1) = q1;
    }

    // MFMA: 2 feature tiles x 4 K-slices, bias preloaded as C
    facc4 acc0 = bfr[0], acc1 = bfr[1];
#pragma unroll
    for (int c = 0; c < 4; ++c) {
      acc0 = __builtin_amdgcn_mfma_f32_16x16x32_bf16(bw[0][c], af[c], acc0, 0, 0, 0);
      acc1 = __builtin_amdgcn_mfma_f32_16x16x32_bf16(bw[1][c], af[c], acc1, 0, 0, 0);
    }

    // (A) previous iteration's sY readback done + this iteration's sX stage visible
    __syncthreads();
    *(floatx4*)((char*)sY + syw)  = acc0;
    *(floatx4*)((char*)sY + syw1) = acc1;
    // (B) sY tile complete
    __syncthreads();
    // linear readback -> 4-KB contiguous global stores (8 complete rows / inst)
#pragma unroll
    for (int s = 0; s < 2; ++s) {
      const int row = (tid >> 5) + s * 8;
      const unsigned bo = (unsigned)(((tid & 31) * 16) ^ ((row & 7) << 4));
      floatx4 v = *(const floatx4*)((const char*)sY + row * 512 + bo);
      *(floatx4*)(yb + (size_t)it * 2048 + (size_t)s * 1024 + tid * 4) = v;
    }
  }
}

extern "C" void kernel_launch(void* const* d_in, const int* in_sizes, int n_in,
                              void* d_out, int out_size, void* d_ws, size_t ws_size,
                              hipStream_t stream) {
  const float* x    = (const float*)d_in[0];
  const float* ang  = (const float*)d_in[1];
  const float* bias = (const float*)d_in[2];
  float* y = (float*)d_out;

  char* ws = (char*)d_ws;
  float* chunks      = (float*)ws;                      // 8 * 64 KiB = 524288 B
  unsigned short* wt = (unsigned short*)(ws + 524288);  // 34816 B

  k_wgen   <<<8,    256, 0, stream>>>(ang, chunks);
  k_combine<<<128,  128, 0, stream>>>(chunks, wt);
  k_gemm   <<<2048, 256, 0, stream>>>(x, wt, bias, y);
}

// Round 8
// 282.361 us; speedup vs baseline: 1.4444x; 1.2165x over previous
//
#include <hip/hip_runtime.h>

typedef float  floatx4  __attribute__((ext_vector_type(4)));
typedef short  bf16x8   __attribute__((ext_vector_type(8)));
typedef float  facc4    __attribute__((ext_vector_type(4)));
typedef unsigned short ushortx4 __attribute__((ext_vector_type(4)));

__device__ __forceinline__ unsigned short f2bf(float f) {
  unsigned u = __builtin_bit_cast(unsigned, f);
  u = u + 0x7fffu + ((u >> 16) & 1u);   // round-to-nearest-even
  return (unsigned short)(u >> 16);
}

// ---------------- K1: chunk partial products (unchanged) ----------------
template <int I0, int I1>
__device__ void gen_chunk(const float* __restrict__ ang, float* __restrict__ out,
                          float* lcs, int tid) {
  constexpr int P0 = I0 * 127 - I0 * (I0 - 1) / 2;
  constexpr int P1 = I1 * 127 - I1 * (I1 - 1) / 2;
  constexpr int NROT = P1 - P0;
  for (int idx = tid; idx < NROT; idx += 256) {
    float s, c;
    sincosf(ang[P0 + idx], &s, &c);
    lcs[2 * idx] = c;
    lcs[2 * idx + 1] = s;
  }
  __syncthreads();
  if (tid >= 128) return;
  float w[128];
#pragma unroll
  for (int k = 0; k < 128; ++k) w[k] = (k == tid) ? 1.0f : 0.0f;
#pragma unroll
  for (int i = I0; i < I1; ++i) {
    float wi = w[i];
#pragma unroll
    for (int j = i + 1; j < 128; ++j) {
      const int p = (i * 127 - (i * (i - 1)) / 2 + (j - i - 1)) - P0;
      const float2 cs2 = *(const float2*)(&lcs[2 * p]);
      const float c = cs2.x, s = cs2.y;
      const float wj = w[j];
      w[j] = fmaf(wj, c, -(wi * s));
      wi   = fmaf(wj, s, wi * c);
    }
    w[i] = wi;
  }
  floatx4* o = (floatx4*)(out + (size_t)tid * 128);
#pragma unroll
  for (int k = 0; k < 32; ++k) {
    floatx4 v;
    v[0] = w[4 * k]; v[1] = w[4 * k + 1]; v[2] = w[4 * k + 2]; v[3] = w[4 * k + 3];
    o[k] = v;
  }
}

__global__ __launch_bounds__(256) void k_wgen(const float* __restrict__ ang,
                                              float* __restrict__ out) {
  __shared__ float lcs[2144];
  const int tid = threadIdx.x;
  switch (blockIdx.x) {
    case 0:  gen_chunk<0,   8>(ang, out + 0 * 16384, lcs, tid); break;
    case 1:  gen_chunk<8,  17>(ang, out + 1 * 16384, lcs, tid); break;
    case 2:  gen_chunk<17, 27>(ang, out + 2 * 16384, lcs, tid); break;
    case 3:  gen_chunk<27, 37>(ang, out + 3 * 16384, lcs, tid); break;
    case 4:  gen_chunk<37, 49>(ang, out + 4 * 16384, lcs, tid); break;
    case 5:  gen_chunk<49, 64>(ang, out + 5 * 16384, lcs, tid); break;
    case 6:  gen_chunk<64, 82>(ang, out + 6 * 16384, lcs, tid); break;
    default: gen_chunk<82, 127>(ang, out + 7 * 16384, lcs, tid); break;
  }
}

// ---------------- K2: combine W = C0*...*C7 -> Wt bf16 [n][136] (unchanged) --------
__global__ __launch_bounds__(128) void k_combine(const float* __restrict__ chunks,
                                                 unsigned short* __restrict__ wt) {
  __shared__ float sv[128];
  const int r = blockIdx.x;
  const int t = threadIdx.x;
  float v = chunks[r * 128 + t];
  for (int m = 1; m < 8; ++m) {
    __syncthreads();
    sv[t] = v;
    __syncthreads();
    const float* Cm = chunks + m * 16384 + t;
    float a0 = 0.f, a1 = 0.f, a2 = 0.f, a3 = 0.f;
#pragma unroll
    for (int k = 0; k < 128; k += 4) {
      a0 = fmaf(sv[k],     Cm[(k)     * 128], a0);
      a1 = fmaf(sv[k + 1], Cm[(k + 1) * 128], a1);
      a2 = fmaf(sv[k + 2], Cm[(k + 2) * 128], a2);
      a3 = fmaf(sv[k + 3], Cm[(k + 3) * 128], a3);
    }
    v = (a0 + a1) + (a2 + a3);
  }
  wt[t * 136 + r] = f2bf(v);
}

// ---------------- K3: y = x @ W + bias ----------------
// Round-7 (resubmitted after broker timeout): spill-free 32 waves/CU.
// Diagnosis: every (..,8) launch_bounds run compiled to VGPR=32 (< the ~60-90
// live regs) -> ~50 dwords/thread scratch spill; at 8 blocks/CU the scratch
// working set overflows per-XCD L2 -> the +100..358 MB WRITE/FETCH
// amplification seen in r3-r6.  Fix: 512-thread blocks, 8 waves, each wave
// owns only 16 features (bw 16 regs, acc 4, prefetch 4, af 16 -> ~58 total),
// __launch_bounds__(512,4) (empirical reg cap 256/minwaves = 64).
// 4 blocks/CU x 8 waves = 32 waves/CU, zero spill.  LDS 16 KB:
// double-buffered 16x128 bf16 x-tile (swizzled) + 16x128 f32 sY transpose
// tile; all global loads/stores fully linear.
__global__ __launch_bounds__(512, 4) void k_gemm(const float* __restrict__ x,
                                                 const unsigned short* __restrict__ wt,
                                                 const float* __restrict__ bias,
                                                 float* __restrict__ y) {
  __shared__ unsigned short sX[2][2048];  // 2 x (16 rows x 128 bf16), swizzled
  __shared__ float sY[2048];              // 16 rows x 128 f32 transpose tile

  const int tid = threadIdx.x;
  const int wv = tid >> 6, lane = tid & 63;
  const int m16 = lane & 15, h = lane >> 4;

  // W fragments: wave wv owns features [wv*16, wv*16+16)
  bf16x8 bw[4];
#pragma unroll
  for (int c = 0; c < 4; ++c)
    bw[c] = *(const bf16x8*)(wt + (size_t)(wv * 16 + m16) * 136 + c * 32 + h * 8);
  facc4 bfr = *(const facc4*)(bias + wv * 16 + h * 4);

  const float* xb = x + (size_t)blockIdx.x * 128 * 128;
  float*       yb = y + (size_t)blockIdx.x * 128 * 128;

  // staging: thread t -> tile row sr=t>>5 (0..15), float col (t&31)*4; 8-B bf16 write
  const int sr = tid >> 5;
  const unsigned stb = (unsigned)(sr * 256 + (((tid & 31) * 8) ^ ((sr & 7) << 4)));
  // sY write: batch row m16, features wv*16 + h*4 .. +4 (16 B), swizzled
  const unsigned syw = (unsigned)(m16 * 512 + ((wv * 64 + h * 16) ^ ((m16 & 7) << 4)));
  // sY read: row sr, cols (t&31)*4 -> linear global store
  const unsigned syr = (unsigned)(sr * 512 + (((tid & 31) * 16) ^ ((sr & 7) << 4)));

  // prologue: stage tile 0, prefetch tile 1
  floatx4 p = *(const floatx4*)(xb + tid * 4);
  {
    ushortx4 q;
#pragma unroll
    for (int i = 0; i < 4; ++i) q[i] = f2bf(p[i]);
    *(ushortx4*)((char*)&sX[0][0] + stb) = q;
  }
  p = *(const floatx4*)(xb + 2048 + tid * 4);
  __syncthreads();

#pragma unroll
  for (int it = 0; it < 8; ++it) {
    const int cur = it & 1;
    // B fragments: lane (m16,h) reads tile row m16, bf16 cols [c*32+h*8, +8)
    bf16x8 af[4];
#pragma unroll
    for (int c = 0; c < 4; ++c)
      af[c] = *(const bf16x8*)((const char*)&sX[cur][0] +
               (unsigned)(m16 * 256 + ((c * 64 + h * 16) ^ ((m16 & 7) << 4))));

    // stage tile it+1 (held in p) into the other buffer
    if (it < 7) {
      ushortx4 q;
#pragma unroll
      for (int i = 0; i < 4; ++i) q[i] = f2bf(p[i]);
      *(ushortx4*)((char*)&sX[cur ^ 1][0] + stb) = q;
    }
    // prefetch tile it+2
    if (it < 6) p = *(const floatx4*)(xb + (size_t)(it + 2) * 2048 + tid * 4);

    // MFMA: 16 features x 16 rows, K=128 in 4 slices; bias preloaded as C
    facc4 acc = bfr;
#pragma unroll
    for (int c = 0; c < 4; ++c)
      acc = __builtin_amdgcn_mfma_f32_16x16x32_bf16(bw[c], af[c], acc, 0, 0, 0);

    // block-level transpose: (A) prev readback + this stage visible
    __syncthreads();
    *(floatx4*)((char*)sY + syw) = acc;
    __syncthreads();  // (B) sY tile complete
    floatx4 v = *(const floatx4*)((const char*)sY + syr);
    *(floatx4*)(yb + (size_t)it * 2048 + tid * 4) = v;  // fully linear 8-KB span
  }
}

extern "C" void kernel_launch(void* const* d_in, const int* in_sizes, int n_in,
                              void* d_out, int out_size, void* d_ws, size_t ws_size,
                              hipStream_t stream) {
  const float* x    = (const float*)d_in[0];
  const float* ang  = (const float*)d_in[1];
  const float* bias = (const float*)d_in[2];
  float* y = (float*)d_out;

  char* ws = (char*)d_ws;
  float* chunks      = (float*)ws;                      // 8 * 64 KiB = 524288 B
  unsigned short* wt = (unsigned short*)(ws + 524288);  // 34816 B

  k_wgen   <<<8,    256, 0, stream>>>(ang, chunks);
  k_combine<<<128,  128, 0, stream>>>(chunks, wt);
  k_gemm   <<<2048, 512, 0, stream>>>(x, wt, bias, y);
}